// Round 2
// baseline (2113.004 us; speedup 1.0000x reference)
//
#include <hip/hip_runtime.h>

#define N_NODES 10000
#define BN_TOT  40000
#define HID     64
#define IN_F    16
#define TCH     32
#define NW      12

// ---------------- degree / dinv ----------------
__global__ void deg_kernel(const int* __restrict__ dst, float* __restrict__ deg, int E) {
    int e = blockIdx.x * blockDim.x + threadIdx.x;
    if (e < E) atomicAdd(&deg[dst[e]], 1.0f);
}

__global__ void dinv_kernel(const float* __restrict__ deg, float* __restrict__ dinv) {
    int i = blockIdx.x * blockDim.x + threadIdx.x;
    if (i < BN_TOT) dinv[i] = (i < N_NODES) ? rsqrtf(deg[i] + 1.0f) : 1.0f;
}

// ---------------- GEMM1: m[bn][64] = x_row(16) @ W1(16x64) ----------------
__global__ void gemm1_kernel(const float* __restrict__ x, const float* __restrict__ W1,
                             float* __restrict__ m, int w) {
    int idx = blockIdx.x * blockDim.x + threadIdx.x;
    if (idx >= BN_TOT * HID) return;
    int bn = idx >> 6, oc = idx & 63;
    int b = bn / N_NODES, n = bn - b * N_NODES;
    const float* xr = x + (((size_t)b * NW + w) * N_NODES + n) * IN_F;
    float s = 0.f;
#pragma unroll
    for (int f = 0; f < IN_F; ++f) s += xr[f] * W1[f * HID + oc];
    m[idx] = s;
}

// ---------------- GEMM2: m2[bn][64] = h_row(64) @ W2(64x64) ----------------
__global__ void gemm2_kernel(const float* __restrict__ h, const float* __restrict__ W2,
                             float* __restrict__ m2) {
    int idx = blockIdx.x * blockDim.x + threadIdx.x;
    if (idx >= BN_TOT * HID) return;
    int bn = idx >> 6, oc = idx & 63;
    const float* hr = h + (size_t)bn * HID;
    float s = 0.f;
#pragma unroll
    for (int ic = 0; ic < HID; ++ic) s += hr[ic] * W2[ic * HID + oc];
    m2[idx] = s;
}

// ---------------- scatter: agg[dst] += dinv[src]*dinv[dst] * m[src] ----------------
__global__ void scatter_kernel(const int* __restrict__ src, const int* __restrict__ dst,
                               const float* __restrict__ dinv, const float* __restrict__ m,
                               float* agg, int E) {
    int tid = blockIdx.x * blockDim.x + threadIdx.x;  // E * 16 threads, 4 ch each
    int e = tid >> 4;
    if (e >= E) return;
    int c4 = (tid & 15) << 2;
    int s = src[e], d = dst[e];
    float ne = dinv[s] * dinv[d];
    const float4 v = *reinterpret_cast<const float4*>(m + (size_t)s * HID + c4);
    float* a = agg + (size_t)d * HID + c4;
    atomicAdd(a + 0, ne * v.x);
    atomicAdd(a + 1, ne * v.y);
    atomicAdd(a + 2, ne * v.z);
    atomicAdd(a + 3, ne * v.w);
}

// ---------------- combine: out = relu(agg + dinv^2*m + bias) ----------------
// NOTE: out may alias agg or m (each thread reads then writes only its own
// element), so no __restrict__ on those.
__global__ void comb_kernel(const float* agg, const float* m,
                            const float* __restrict__ dinv, const float* __restrict__ bias,
                            float* out) {
    int i = blockIdx.x * blockDim.x + threadIdx.x;
    if (i >= BN_TOT * HID) return;
    int bn = i >> 6, c = i & 63;
    float dv = dinv[bn];
    float a = (bn < N_NODES) ? agg[i] : 0.f;   // rows >= N_NODES never aggregated
    float v = a + dv * dv * m[i] + bias[c];
    out[i] = v > 0.f ? v : 0.f;
}

// ---------------- fused conv1(t=10,11) + conv2(t=11) + fc ----------------
// H layout: [3][BN_TOT][HID], slots 0,1,2 = GCN outputs at w = 9,10,11.
__global__ void convfc_kernel(const float* __restrict__ H,
                              const float* __restrict__ w1c, const float* __restrict__ b1c,
                              const float* __restrict__ w2c, const float* __restrict__ b2c,
                              const float* __restrict__ fcw, const float* __restrict__ fcb,
                              float* __restrict__ out) {
    __shared__ float h[3][HID];
    __shared__ float c1[2][TCH];
    __shared__ float c2s[TCH];
    int bn = blockIdx.x, t = threadIdx.x;
    h[0][t] = H[(size_t)0 * BN_TOT * HID + (size_t)bn * HID + t];
    h[1][t] = H[(size_t)1 * BN_TOT * HID + (size_t)bn * HID + t];
    h[2][t] = H[(size_t)2 * BN_TOT * HID + (size_t)bn * HID + t];
    __syncthreads();
    if (t < TCH) {
        // conv1 at t=10: taps H9,H10,H11 (k=0,1,2); at t=11: taps H10,H11 (k=0,1), k=2 is pad
        float s10 = b1c[t], s11 = b1c[t];
#pragma unroll
        for (int ic = 0; ic < HID; ++ic) {
            float w0 = w1c[t * HID * 3 + ic * 3 + 0];
            float w1 = w1c[t * HID * 3 + ic * 3 + 1];
            float w2 = w1c[t * HID * 3 + ic * 3 + 2];
            s10 += h[0][ic] * w0 + h[1][ic] * w1 + h[2][ic] * w2;
            s11 += h[1][ic] * w0 + h[2][ic] * w1;
        }
        c1[0][t] = s10 > 0.f ? s10 : 0.f;
        c1[1][t] = s11 > 0.f ? s11 : 0.f;
    }
    __syncthreads();
    if (t < TCH) {
        // conv2 at t=11: taps c1[10] (k=0), c1[11] (k=1), k=2 is pad
        float s = b2c[t];
#pragma unroll
        for (int ic = 0; ic < TCH; ++ic)
            s += c1[0][ic] * w2c[t * TCH * 3 + ic * 3 + 0]
               + c1[1][ic] * w2c[t * TCH * 3 + ic * 3 + 1];
        s = s > 0.f ? s : 0.f;
        c2s[t] = s * fcw[t];
    }
    __syncthreads();
    if (t == 0) {
        float s = fcb[0];
#pragma unroll
        for (int ic = 0; ic < TCH; ++ic) s += c2s[ic];
        out[bn] = s;
    }
}

extern "C" void kernel_launch(void* const* d_in, const int* in_sizes, int n_in,
                              void* d_out, int out_size, void* d_ws, size_t ws_size,
                              hipStream_t stream) {
    const float* x   = (const float*)d_in[0];
    const int*   ei  = (const int*)d_in[1];
    const float* W1  = (const float*)d_in[2];
    const float* b1  = (const float*)d_in[3];
    const float* W2  = (const float*)d_in[4];
    const float* b2  = (const float*)d_in[5];
    const float* c1w = (const float*)d_in[6];
    const float* c1b = (const float*)d_in[7];
    const float* c2w = (const float*)d_in[8];
    const float* c2b = (const float*)d_in[9];
    const float* fcw = (const float*)d_in[10];
    const float* fcb = (const float*)d_in[11];
    float* out = (float*)d_out;

    const int E = in_sizes[1] / 2;
    const int* src = ei;
    const int* dst = ei + E;

    float* ws   = (float*)d_ws;
    float* deg  = ws;                            // 10000 (padded to 16384)
    float* dinv = ws + 16384;                    // 40000 (padded to 40960)
    float* bufA = dinv + 40960;                  // BN*HID
    float* bufB = bufA + (size_t)BN_TOT * HID;   // BN*HID
    float* Hbuf = bufB + (size_t)BN_TOT * HID;   // 3 * BN*HID

    hipMemsetAsync(deg, 0, N_NODES * sizeof(float), stream);
    deg_kernel<<<(E + 255) / 256, 256, 0, stream>>>(dst, deg, E);
    dinv_kernel<<<(BN_TOT + 255) / 256, 256, 0, stream>>>(deg, dinv);

    const int NTHREAD = BN_TOT * HID;           // 2,560,000
    const int wlist[3] = {9, 10, 11};
    for (int i = 0; i < 3; ++i) {
        int w = wlist[i];
        float* Hw = Hbuf + (size_t)i * BN_TOT * HID;

        gemm1_kernel<<<(NTHREAD + 255) / 256, 256, 0, stream>>>(x, W1, bufA, w);
        hipMemsetAsync(bufB, 0, (size_t)N_NODES * HID * sizeof(float), stream);
        scatter_kernel<<<(E * 16 + 255) / 256, 256, 0, stream>>>(src, dst, dinv, bufA, bufB, E);
        comb_kernel<<<(NTHREAD + 255) / 256, 256, 0, stream>>>(bufB, bufA, dinv, b1, bufA);

        gemm2_kernel<<<(NTHREAD + 255) / 256, 256, 0, stream>>>(bufA, W2, bufB);
        hipMemsetAsync(Hw, 0, (size_t)N_NODES * HID * sizeof(float), stream);
        scatter_kernel<<<(E * 16 + 255) / 256, 256, 0, stream>>>(src, dst, dinv, bufB, Hw, E);
        comb_kernel<<<(NTHREAD + 255) / 256, 256, 0, stream>>>(Hw, bufB, dinv, b2, Hw);
    }

    convfc_kernel<<<BN_TOT, 64, 0, stream>>>(Hbuf, c1w, c1b, c2w, c2b, fcw, fcb, out);
}

// Round 3
// 506.287 us; speedup vs baseline: 4.1735x; 4.1735x over previous
//
#include <hip/hip_runtime.h>

#define N_NODES 10000
#define BN_TOT  40000
#define HID     64
#define IN_F    16
#define TCH     32
#define NW      12

// ---------------- histogram of dst (also gives degree: deg = cnt + 1) --------
__global__ void hist_kernel(const int* __restrict__ dst, int* __restrict__ cnt, int E) {
    int e = blockIdx.x * blockDim.x + threadIdx.x;
    if (e < E) atomicAdd(&cnt[dst[e]], 1);
}

// ---------------- single-block exclusive scan over 10000 bins ----------------
// Also writes fill_pos (a second copy for the atomic bucket fill) and
// dinv[i] = rsqrt(cnt[i] + 1) for i < N_NODES.
__global__ __launch_bounds__(1024) void scan_kernel(const int* __restrict__ cnt,
                                                    int* __restrict__ row_ptr,
                                                    int* __restrict__ fill_pos,
                                                    float* __restrict__ dinv) {
    __shared__ int part[1024];
    int t = threadIdx.x;
    int base = t * 10;                       // 1024*10 = 10240 >= 10000
    int s = 0;
#pragma unroll
    for (int k = 0; k < 10; ++k) {
        int b = base + k;
        if (b < N_NODES) s += cnt[b];
    }
    part[t] = s;
    __syncthreads();
    for (int off = 1; off < 1024; off <<= 1) {   // Hillis-Steele inclusive scan
        int v = 0;
        if (t >= off) v = part[t - off];
        __syncthreads();
        part[t] += v;
        __syncthreads();
    }
    int running = (t == 0) ? 0 : part[t - 1];    // exclusive base for this chunk
#pragma unroll
    for (int k = 0; k < 10; ++k) {
        int b = base + k;
        if (b < N_NODES) {
            row_ptr[b]  = running;
            fill_pos[b] = running;
            int c = cnt[b];
            dinv[b] = rsqrtf((float)c + 1.0f);
            running += c;
        }
    }
    if (t == 1023) row_ptr[N_NODES] = part[1023];
}

// ---------------- CSR bucket fill: col[] = src, ne[] = dinv[s]*dinv[d] -------
__global__ void fill_kernel(const int* __restrict__ src, const int* __restrict__ dst,
                            const float* __restrict__ dinv,
                            int* __restrict__ fill_pos,
                            int* __restrict__ col, float* __restrict__ ne, int E) {
    int e = blockIdx.x * blockDim.x + threadIdx.x;
    if (e >= E) return;
    int s = src[e], d = dst[e];
    int pos = atomicAdd(&fill_pos[d], 1);
    col[pos] = s;
    ne[pos]  = dinv[s] * dinv[d];
}

// ---------------- GEMM1: m[bn][64] = x_row(16) @ W1(16x64) -------------------
__global__ void gemm1_kernel(const float* __restrict__ x, const float* __restrict__ W1,
                             float* __restrict__ m, int w) {
    int idx = blockIdx.x * blockDim.x + threadIdx.x;
    if (idx >= BN_TOT * HID) return;
    int bn = idx >> 6, oc = idx & 63;
    int b = bn / N_NODES, n = bn - b * N_NODES;
    const float* xr = x + (((size_t)b * NW + w) * N_NODES + n) * IN_F;
    float s = 0.f;
#pragma unroll
    for (int f = 0; f < IN_F; ++f) s += xr[f] * W1[f * HID + oc];
    m[idx] = s;
}

// ---- gatherA: h1 = relu(csr_agg(m1) + dinv^2*m1 + b1); m2 = h1 @ W2 ---------
// One wave per row; lane = channel. h1 row lives across the wave's 64 lanes,
// broadcast through LDS for the 64x64 GEMM2 (W2 is 16 KB, L1-resident).
__global__ __launch_bounds__(256) void gatherA_kernel(
        const float* __restrict__ m, const int* __restrict__ row_ptr,
        const int* __restrict__ col, const float* __restrict__ ne,
        const float* __restrict__ dinv, const float* __restrict__ b1,
        const float* __restrict__ W2, float* __restrict__ m2) {
    __shared__ float hs[4][HID];
    int gid = blockIdx.x * blockDim.x + threadIdx.x;   // grid exact: 40000 waves
    int row = gid >> 6;
    int lane = threadIdx.x & 63;
    int wv = threadIdx.x >> 6;
    float mval = m[(size_t)row * HID + lane];
    float s;
    if (row < N_NODES) {
        float dv = dinv[row];
        s = dv * dv * mval;
        int j = row_ptr[row], end = row_ptr[row + 1];
        for (; j + 1 < end; j += 2) {                  // 2-edge unroll for ILP
            int c0 = col[j], c1 = col[j + 1];
            float w0 = ne[j], w1 = ne[j + 1];
            s += w0 * m[(size_t)c0 * HID + lane];
            s += w1 * m[(size_t)c1 * HID + lane];
        }
        if (j < end) s += ne[j] * m[(size_t)col[j] * HID + lane];
    } else {
        s = mval;                                      // rows >= N_NODES: deg=1, agg=0
    }
    s += b1[lane];
    s = s > 0.f ? s : 0.f;
    hs[wv][lane] = s;
    __syncthreads();
    float s2 = 0.f;
#pragma unroll
    for (int ic = 0; ic < HID; ++ic) s2 += hs[wv][ic] * W2[ic * HID + lane];
    m2[(size_t)row * HID + lane] = s2;
}

// ---- gatherB: H = relu(csr_agg(m2) + dinv^2*m2 + b2) ------------------------
__global__ __launch_bounds__(256) void gatherB_kernel(
        const float* __restrict__ m, const int* __restrict__ row_ptr,
        const int* __restrict__ col, const float* __restrict__ ne,
        const float* __restrict__ dinv, const float* __restrict__ b2,
        float* __restrict__ out) {
    int gid = blockIdx.x * blockDim.x + threadIdx.x;
    int row = gid >> 6;
    int lane = threadIdx.x & 63;
    float mval = m[(size_t)row * HID + lane];
    float s;
    if (row < N_NODES) {
        float dv = dinv[row];
        s = dv * dv * mval;
        int j = row_ptr[row], end = row_ptr[row + 1];
        for (; j + 1 < end; j += 2) {
            int c0 = col[j], c1 = col[j + 1];
            float w0 = ne[j], w1 = ne[j + 1];
            s += w0 * m[(size_t)c0 * HID + lane];
            s += w1 * m[(size_t)c1 * HID + lane];
        }
        if (j < end) s += ne[j] * m[(size_t)col[j] * HID + lane];
    } else {
        s = mval;
    }
    s += b2[lane];
    out[(size_t)row * HID + lane] = s > 0.f ? s : 0.f;
}

// ---------------- fused conv1(t=10,11) + conv2(t=11) + fc --------------------
// H layout: [3][BN_TOT][HID], slots 0,1,2 = GCN outputs at w = 9,10,11.
__global__ void convfc_kernel(const float* __restrict__ H,
                              const float* __restrict__ w1c, const float* __restrict__ b1c,
                              const float* __restrict__ w2c, const float* __restrict__ b2c,
                              const float* __restrict__ fcw, const float* __restrict__ fcb,
                              float* __restrict__ out) {
    __shared__ float h[3][HID];
    __shared__ float c1[2][TCH];
    __shared__ float c2s[TCH];
    int bn = blockIdx.x, t = threadIdx.x;
    h[0][t] = H[(size_t)0 * BN_TOT * HID + (size_t)bn * HID + t];
    h[1][t] = H[(size_t)1 * BN_TOT * HID + (size_t)bn * HID + t];
    h[2][t] = H[(size_t)2 * BN_TOT * HID + (size_t)bn * HID + t];
    __syncthreads();
    if (t < TCH) {
        // conv1 at t=10: taps H9,H10,H11 (k=0,1,2); at t=11: taps H10,H11 (k=0,1)
        float s10 = b1c[t], s11 = b1c[t];
#pragma unroll
        for (int ic = 0; ic < HID; ++ic) {
            float w0 = w1c[t * HID * 3 + ic * 3 + 0];
            float w1 = w1c[t * HID * 3 + ic * 3 + 1];
            float w2 = w1c[t * HID * 3 + ic * 3 + 2];
            s10 += h[0][ic] * w0 + h[1][ic] * w1 + h[2][ic] * w2;
            s11 += h[1][ic] * w0 + h[2][ic] * w1;
        }
        c1[0][t] = s10 > 0.f ? s10 : 0.f;
        c1[1][t] = s11 > 0.f ? s11 : 0.f;
    }
    __syncthreads();
    if (t < TCH) {
        float s = b2c[t];
#pragma unroll
        for (int ic = 0; ic < TCH; ++ic)
            s += c1[0][ic] * w2c[t * TCH * 3 + ic * 3 + 0]
               + c1[1][ic] * w2c[t * TCH * 3 + ic * 3 + 1];
        s = s > 0.f ? s : 0.f;
        c2s[t] = s * fcw[t];
    }
    __syncthreads();
    if (t == 0) {
        float s = fcb[0];
#pragma unroll
        for (int ic = 0; ic < TCH; ++ic) s += c2s[ic];
        out[bn] = s;
    }
}

extern "C" void kernel_launch(void* const* d_in, const int* in_sizes, int n_in,
                              void* d_out, int out_size, void* d_ws, size_t ws_size,
                              hipStream_t stream) {
    const float* x   = (const float*)d_in[0];
    const int*   ei  = (const int*)d_in[1];
    const float* W1  = (const float*)d_in[2];
    const float* b1  = (const float*)d_in[3];
    const float* W2  = (const float*)d_in[4];
    const float* b2  = (const float*)d_in[5];
    const float* c1w = (const float*)d_in[6];
    const float* c1b = (const float*)d_in[7];
    const float* c2w = (const float*)d_in[8];
    const float* c2b = (const float*)d_in[9];
    const float* fcw = (const float*)d_in[10];
    const float* fcb = (const float*)d_in[11];
    float* out = (float*)d_out;

    const int E = in_sizes[1] / 2;
    const int* src = ei;
    const int* dst = ei + E;

    // ---- workspace layout ----
    int*   cnt      = (int*)d_ws;                  // 10000 (pad 10240)
    int*   row_ptr  = cnt + 10240;                 // 10001 (pad 10240)
    int*   fill_pos = row_ptr + 10240;             // 10000 (pad 10240)
    int*   colb     = fill_pos + 10240;            // E
    float* neb      = (float*)(colb + E);          // E
    float* dinv     = neb + E;                     // 10000 (pad 10240)
    float* mA       = dinv + 10240;                // BN*HID
    float* mB       = mA + (size_t)BN_TOT * HID;   // BN*HID
    float* Hbuf     = mB + (size_t)BN_TOT * HID;   // 3 * BN*HID

    // ---- CSR build (once; shared by all 6 aggregations) ----
    hipMemsetAsync(cnt, 0, N_NODES * sizeof(int), stream);
    hist_kernel<<<(E + 255) / 256, 256, 0, stream>>>(dst, cnt, E);
    scan_kernel<<<1, 1024, 0, stream>>>(cnt, row_ptr, fill_pos, dinv);
    fill_kernel<<<(E + 255) / 256, 256, 0, stream>>>(src, dst, dinv, fill_pos, colb, neb, E);

    const int NTHREAD = BN_TOT * HID;              // 2,560,000 (grid exact: 10000 blocks)
    const int wlist[3] = {9, 10, 11};
    for (int i = 0; i < 3; ++i) {
        float* Hw = Hbuf + (size_t)i * BN_TOT * HID;
        gemm1_kernel<<<NTHREAD / 256, 256, 0, stream>>>(x, W1, mA, wlist[i]);
        gatherA_kernel<<<NTHREAD / 256, 256, 0, stream>>>(mA, row_ptr, colb, neb, dinv, b1, W2, mB);
        gatherB_kernel<<<NTHREAD / 256, 256, 0, stream>>>(mB, row_ptr, colb, neb, dinv, b2, Hw);
    }

    convfc_kernel<<<BN_TOT, 64, 0, stream>>>(Hbuf, c1w, c1b, c2w, c2b, fcw, fcb, out);
}

// Round 6
// 252.859 us; speedup vs baseline: 8.3564x; 2.0022x over previous
//
#include <hip/hip_runtime.h>

#define N_NODES 10000
#define BN_TOT  40000
#define HID     64
#define IN_F    16
#define TCH     32
#define NW      12

// ---------------- histogram of dst (degree = cnt + 1) ------------------------
__global__ void hist_kernel(const int* __restrict__ dst, int* __restrict__ cnt, int E) {
    int e = blockIdx.x * blockDim.x + threadIdx.x;
    if (e < E) atomicAdd(&cnt[dst[e]], 1);
}

// ---------------- single-block exclusive scan over 10000 bins ----------------
__global__ __launch_bounds__(1024) void scan_kernel(const int* __restrict__ cnt,
                                                    int* __restrict__ row_ptr,
                                                    int* __restrict__ fill_pos,
                                                    float* __restrict__ dinv) {
    __shared__ int part[1024];
    int t = threadIdx.x;
    int base = t * 10;
    int s = 0;
#pragma unroll
    for (int k = 0; k < 10; ++k) {
        int b = base + k;
        if (b < N_NODES) s += cnt[b];
    }
    part[t] = s;
    __syncthreads();
    for (int off = 1; off < 1024; off <<= 1) {
        int v = 0;
        if (t >= off) v = part[t - off];
        __syncthreads();
        part[t] += v;
        __syncthreads();
    }
    int running = (t == 0) ? 0 : part[t - 1];
#pragma unroll
    for (int k = 0; k < 10; ++k) {
        int b = base + k;
        if (b < N_NODES) {
            row_ptr[b]  = running;
            fill_pos[b] = running;
            int c = cnt[b];
            dinv[b] = rsqrtf((float)c + 1.0f);
            running += c;
        }
    }
    if (t == 1023) row_ptr[N_NODES] = part[1023];
}

// ---------------- CSR bucket fill -------------------------------------------
__global__ void fill_kernel(const int* __restrict__ src, const int* __restrict__ dst,
                            const float* __restrict__ dinv,
                            int* __restrict__ fill_pos,
                            int* __restrict__ col, float* __restrict__ ne, int E) {
    int e = blockIdx.x * blockDim.x + threadIdx.x;
    if (e >= E) return;
    int s = src[e], d = dst[e];
    int pos = atomicAdd(&fill_pos[d], 1);
    col[pos] = s;
    ne[pos]  = dinv[s] * dinv[d];
}

// ---------------- GEMM1 x3: m[t][bn][64] = x_row(16, w=9+t) @ W1 -------------
__global__ __launch_bounds__(256) void gemm1_kernel(const float* __restrict__ x,
                                                    const float* __restrict__ W1,
                                                    float* __restrict__ m) {
    int idx = blockIdx.x * blockDim.x + threadIdx.x;
    int oc = idx & 63;
    int bn = __builtin_amdgcn_readfirstlane(idx >> 6);   // wave-uniform -> s_loads on x
    int b = bn / N_NODES, n = bn - b * N_NODES;
    const float* xb = x + ((size_t)b * NW) * N_NODES * IN_F + (size_t)n * IN_F;
    const size_t S = (size_t)BN_TOT * HID;
    float s0 = 0.f, s1 = 0.f, s2 = 0.f;
#pragma unroll
    for (int f = 0; f < IN_F; ++f) {
        float wv = W1[f * HID + oc];
        s0 += xb[(size_t)9  * N_NODES * IN_F + f] * wv;
        s1 += xb[(size_t)10 * N_NODES * IN_F + f] * wv;
        s2 += xb[(size_t)11 * N_NODES * IN_F + f] * wv;
    }
    m[idx] = s0;
    m[S + idx] = s1;
    m[2 * S + idx] = s2;
}

// ---- gatherA x3: h1 = relu(agg(m1)+dinv^2*m1+b1); m2 = h1 @ W2 --------------
// One wave per row, lane = channel, 3 timesteps per edge visit.
__global__ __launch_bounds__(256) void gatherA_kernel(
        const float* __restrict__ m, const int* __restrict__ row_ptr,
        const int* __restrict__ col, const float* __restrict__ ne,
        const float* __restrict__ dinv, const float* __restrict__ b1,
        const float* __restrict__ W2, float* __restrict__ m2) {
    __shared__ float hs[4][3][HID];
    int gid = blockIdx.x * blockDim.x + threadIdx.x;
    int lane = threadIdx.x & 63;
    int wv = threadIdx.x >> 6;
    int row = __builtin_amdgcn_readfirstlane(gid >> 6);  // -> s_loads on CSR
    const size_t S = (size_t)BN_TOT * HID;
    size_t ro = (size_t)row * HID + lane;
    float m0 = m[ro], m1v = m[S + ro], m2v = m[2 * S + ro];
    float s0, s1, s2;
    if (row < N_NODES) {
        float dv = dinv[row];
        float sn = dv * dv;
        s0 = sn * m0; s1 = sn * m1v; s2 = sn * m2v;
        int j = row_ptr[row], end = row_ptr[row + 1];
        for (; j + 1 < end; j += 2) {
            int c0 = col[j], c1 = col[j + 1];
            float w0 = ne[j], w1 = ne[j + 1];
            size_t o0 = (size_t)c0 * HID + lane, o1 = (size_t)c1 * HID + lane;
            s0 += w0 * m[o0] + w1 * m[o1];
            s1 += w0 * m[S + o0] + w1 * m[S + o1];
            s2 += w0 * m[2 * S + o0] + w1 * m[2 * S + o1];
        }
        if (j < end) {
            float w = ne[j];
            size_t o = (size_t)col[j] * HID + lane;
            s0 += w * m[o]; s1 += w * m[S + o]; s2 += w * m[2 * S + o];
        }
    } else {
        s0 = m0; s1 = m1v; s2 = m2v;   // deg=1, no in-edges
    }
    float bb = b1[lane];
    hs[wv][0][lane] = fmaxf(s0 + bb, 0.f);
    hs[wv][1][lane] = fmaxf(s1 + bb, 0.f);
    hs[wv][2][lane] = fmaxf(s2 + bb, 0.f);
    __syncthreads();
    float t0 = 0.f, t1 = 0.f, t2 = 0.f;
#pragma unroll
    for (int ic = 0; ic < HID; ++ic) {
        float w2v = W2[ic * HID + lane];
        t0 += hs[wv][0][ic] * w2v;
        t1 += hs[wv][1][ic] * w2v;
        t2 += hs[wv][2][ic] * w2v;
    }
    m2[ro] = t0;
    m2[S + ro] = t1;
    m2[2 * S + ro] = t2;
}

// ---- gatherB x3: H[t] = relu(agg(m2)+dinv^2*m2+b2) --------------------------
__global__ __launch_bounds__(256) void gatherB_kernel(
        const float* __restrict__ m, const int* __restrict__ row_ptr,
        const int* __restrict__ col, const float* __restrict__ ne,
        const float* __restrict__ dinv, const float* __restrict__ b2,
        float* __restrict__ out) {
    int gid = blockIdx.x * blockDim.x + threadIdx.x;
    int lane = threadIdx.x & 63;
    int row = __builtin_amdgcn_readfirstlane(gid >> 6);
    const size_t S = (size_t)BN_TOT * HID;
    size_t ro = (size_t)row * HID + lane;
    float m0 = m[ro], m1v = m[S + ro], m2v = m[2 * S + ro];
    float s0, s1, s2;
    if (row < N_NODES) {
        float dv = dinv[row];
        float sn = dv * dv;
        s0 = sn * m0; s1 = sn * m1v; s2 = sn * m2v;
        int j = row_ptr[row], end = row_ptr[row + 1];
        for (; j + 1 < end; j += 2) {
            int c0 = col[j], c1 = col[j + 1];
            float w0 = ne[j], w1 = ne[j + 1];
            size_t o0 = (size_t)c0 * HID + lane, o1 = (size_t)c1 * HID + lane;
            s0 += w0 * m[o0] + w1 * m[o1];
            s1 += w0 * m[S + o0] + w1 * m[S + o1];
            s2 += w0 * m[2 * S + o0] + w1 * m[2 * S + o1];
        }
        if (j < end) {
            float w = ne[j];
            size_t o = (size_t)col[j] * HID + lane;
            s0 += w * m[o]; s1 += w * m[S + o]; s2 += w * m[2 * S + o];
        }
    } else {
        s0 = m0; s1 = m1v; s2 = m2v;
    }
    float bb = b2[lane];
    out[ro] = fmaxf(s0 + bb, 0.f);
    out[S + ro] = fmaxf(s1 + bb, 0.f);
    out[2 * S + ro] = fmaxf(s2 + bb, 0.f);
}

// ---------------- conv1(t=10,11) + conv2(t=11) + fc, register-tiled ----------
// 2 threads per node: half h owns out-channels h*16..h*16+15. Weights via
// scalar loads (readfirstlane-forced uniform). c1 exchanged through LDS.
#define CB_NODES 128
__global__ __launch_bounds__(256) void convfc_kernel(
        const float* __restrict__ H,   // [3][BN][64], slots = w 9,10,11
        const float* __restrict__ w1c, const float* __restrict__ b1c,
        const float* __restrict__ w2c, const float* __restrict__ b2c,
        const float* __restrict__ fcw, const float* __restrict__ fcb,
        float* __restrict__ out) {
    __shared__ float c1s[CB_NODES][65];   // [node][pos*32+oc], pad->conflict-free
    __shared__ float c2p[CB_NODES][2];
    int t = threadIdx.x;
    int wv = t >> 6, lane = t & 63;
    int nodeLocal = (wv >> 1) * 64 + lane;             // waves{0,1}:0..63  {2,3}:64..127
    int half = __builtin_amdgcn_readfirstlane(wv & 1); // wave-uniform -> s_loads
    int node0 = blockIdx.x * CB_NODES + nodeLocal;
    int node = node0 < BN_TOT ? node0 : BN_TOT - 1;    // clamp tail (store guarded)
    const size_t S = (size_t)BN_TOT * HID;
    const float* h9  = H + (size_t)node * HID;
    const float* h10 = H + S + (size_t)node * HID;
    const float* h11 = H + 2 * S + (size_t)node * HID;

    float a10[16], a11[16];
#pragma unroll
    for (int j = 0; j < 16; ++j) {
        float bb = b1c[half * 16 + j];
        a10[j] = bb; a11[j] = bb;
    }
    for (int ic4 = 0; ic4 < 16; ++ic4) {
        float4 v9  = *reinterpret_cast<const float4*>(h9  + ic4 * 4);
        float4 v10 = *reinterpret_cast<const float4*>(h10 + ic4 * 4);
        float4 v11 = *reinterpret_cast<const float4*>(h11 + ic4 * 4);
        float p9[4]  = {v9.x,  v9.y,  v9.z,  v9.w};
        float p10[4] = {v10.x, v10.y, v10.z, v10.w};
        float p11[4] = {v11.x, v11.y, v11.z, v11.w};
#pragma unroll
        for (int kk = 0; kk < 4; ++kk) {
            int ic = ic4 * 4 + kk;
#pragma unroll
            for (int j = 0; j < 16; ++j) {
                int oc = half * 16 + j;
                float w0 = w1c[oc * 192 + ic * 3 + 0];
                float w1 = w1c[oc * 192 + ic * 3 + 1];
                float w2 = w1c[oc * 192 + ic * 3 + 2];
                a10[j] += p9[kk]  * w0 + p10[kk] * w1 + p11[kk] * w2;
                a11[j] += p10[kk] * w0 + p11[kk] * w1;
            }
        }
    }
#pragma unroll
    for (int j = 0; j < 16; ++j) {
        int oc = half * 16 + j;
        c1s[nodeLocal][oc]      = fmaxf(a10[j], 0.f);  // conv1 @ t=10
        c1s[nodeLocal][32 + oc] = fmaxf(a11[j], 0.f);  // conv1 @ t=11
    }
    __syncthreads();

    float a2[16];
#pragma unroll
    for (int j = 0; j < 16; ++j) a2[j] = b2c[half * 16 + j];
#pragma unroll
    for (int ic = 0; ic < TCH; ++ic) {
        float c10 = c1s[nodeLocal][ic];
        float c11 = c1s[nodeLocal][32 + ic];
#pragma unroll
        for (int j = 0; j < 16; ++j) {
            int oc = half * 16 + j;
            a2[j] += c10 * w2c[oc * 96 + ic * 3 + 0]
                   + c11 * w2c[oc * 96 + ic * 3 + 1];
        }
    }
    float p = 0.f;
#pragma unroll
    for (int j = 0; j < 16; ++j) p += fmaxf(a2[j], 0.f) * fcw[half * 16 + j];
    c2p[nodeLocal][half] = p;
    __syncthreads();
    if ((wv & 1) == 0 && node0 < BN_TOT)
        out[node0] = c2p[nodeLocal][0] + c2p[nodeLocal][1] + fcb[0];
}

extern "C" void kernel_launch(void* const* d_in, const int* in_sizes, int n_in,
                              void* d_out, int out_size, void* d_ws, size_t ws_size,
                              hipStream_t stream) {
    const float* x   = (const float*)d_in[0];
    const int*   ei  = (const int*)d_in[1];
    const float* W1  = (const float*)d_in[2];
    const float* b1  = (const float*)d_in[3];
    const float* W2  = (const float*)d_in[4];
    const float* b2  = (const float*)d_in[5];
    const float* c1w = (const float*)d_in[6];
    const float* c1b = (const float*)d_in[7];
    const float* c2w = (const float*)d_in[8];
    const float* c2b = (const float*)d_in[9];
    const float* fcw = (const float*)d_in[10];
    const float* fcb = (const float*)d_in[11];
    float* out = (float*)d_out;

    const int E = in_sizes[1] / 2;
    const int* src = ei;
    const int* dst = ei + E;

    // ---- workspace layout (H aliases nothing live: mA dead after gatherA) ---
    const size_t S = (size_t)BN_TOT * HID;
    int*   cnt      = (int*)d_ws;                  // 10000 (pad 10240)
    int*   row_ptr  = cnt + 10240;                 // 10001 (pad 10240)
    int*   fill_pos = row_ptr + 10240;             // 10000 (pad 10240)
    int*   colb     = fill_pos + 10240;            // E
    float* neb      = (float*)(colb + E);          // E
    float* dinv     = neb + E;                     // 10000 (pad 10240)
    float* mA       = dinv + 10240;                // 3*S  (later reused as H)
    float* mB       = mA + 3 * S;                  // 3*S
    float* Hbuf     = mA;                          // alias: mA dead after gatherA

    // ---- CSR build (shared by both aggregations, all timesteps) ----
    hipMemsetAsync(cnt, 0, N_NODES * sizeof(int), stream);
    hist_kernel<<<(E + 255) / 256, 256, 0, stream>>>(dst, cnt, E);
    scan_kernel<<<1, 1024, 0, stream>>>(cnt, row_ptr, fill_pos, dinv);
    fill_kernel<<<(E + 255) / 256, 256, 0, stream>>>(src, dst, dinv, fill_pos, colb, neb, E);

    const int NT = BN_TOT * HID;                   // 2,560,000
    gemm1_kernel <<<NT / 256, 256, 0, stream>>>(x, W1, mA);
    gatherA_kernel<<<NT / 256, 256, 0, stream>>>(mA, row_ptr, colb, neb, dinv, b1, W2, mB);
    gatherB_kernel<<<NT / 256, 256, 0, stream>>>(mB, row_ptr, colb, neb, dinv, b2, Hbuf);

    convfc_kernel<<<(BN_TOT + CB_NODES - 1) / CB_NODES, 256, 0, stream>>>(
        Hbuf, c1w, c1b, c2w, c2b, fcw, fcb, out);
}

// Round 7
// 214.597 us; speedup vs baseline: 9.8464x; 1.1783x over previous
//
#include <hip/hip_runtime.h>

#define N_NODES 10000
#define BN_TOT  40000
#define HID     64
#define IN_F    16
#define TCH     32
#define NW      12

// ---------------- histogram of dst (degree = cnt + 1) ------------------------
__global__ void hist_kernel(const int* __restrict__ dst, int* __restrict__ cnt, int E) {
    int e = blockIdx.x * blockDim.x + threadIdx.x;
    if (e < E) atomicAdd(&cnt[dst[e]], 1);
}

// ---------------- single-block exclusive scan over 10000 bins ----------------
__global__ __launch_bounds__(1024) void scan_kernel(const int* __restrict__ cnt,
                                                    int* __restrict__ row_ptr,
                                                    int* __restrict__ fill_pos,
                                                    float* __restrict__ dinv) {
    __shared__ int part[1024];
    int t = threadIdx.x;
    int base = t * 10;
    int s = 0;
#pragma unroll
    for (int k = 0; k < 10; ++k) {
        int b = base + k;
        if (b < N_NODES) s += cnt[b];
    }
    part[t] = s;
    __syncthreads();
    for (int off = 1; off < 1024; off <<= 1) {
        int v = 0;
        if (t >= off) v = part[t - off];
        __syncthreads();
        part[t] += v;
        __syncthreads();
    }
    int running = (t == 0) ? 0 : part[t - 1];
#pragma unroll
    for (int k = 0; k < 10; ++k) {
        int b = base + k;
        if (b < N_NODES) {
            row_ptr[b]  = running;
            fill_pos[b] = running;
            int c = cnt[b];
            dinv[b] = rsqrtf((float)c + 1.0f);
            running += c;
        }
    }
    if (t == 1023) row_ptr[N_NODES] = part[1023];
}

// ---------------- CSR bucket fill -------------------------------------------
__global__ void fill_kernel(const int* __restrict__ src, const int* __restrict__ dst,
                            const float* __restrict__ dinv,
                            int* __restrict__ fill_pos,
                            int* __restrict__ col, float* __restrict__ ne, int E) {
    int e = blockIdx.x * blockDim.x + threadIdx.x;
    if (e >= E) return;
    int s = src[e], d = dst[e];
    int pos = atomicAdd(&fill_pos[d], 1);
    col[pos] = s;
    ne[pos]  = dinv[s] * dinv[d];
}

// ---------------- transpose conv weights for coalesced lane reads ------------
// w1t[(ic*3+k)*32 + tc] = c1w[tc*192 + ic*3 + k]   (6144 elems)
// w2t[(ic*2+k)*32 + tc] = c2w[tc*96  + ic*3 + k]   (2048 elems, k in {0,1})
__global__ void prep_kernel(const float* __restrict__ c1w, const float* __restrict__ c2w,
                            float* __restrict__ w1t, float* __restrict__ w2t) {
    int idx = blockIdx.x * blockDim.x + threadIdx.x;   // 8192 threads
    if (idx < 6144) {
        int tc = idx & 31, r = idx >> 5;               // r = ic*3+k
        w1t[idx] = c1w[tc * 192 + r];
    } else {
        int i2 = idx - 6144;
        int tc = i2 & 31, r = i2 >> 5;                 // r = ic*2+k
        int ic = r >> 1, k = r & 1;
        w2t[i2] = c2w[tc * 96 + ic * 3 + k];
    }
}

// ---------------- GEMM1 x3: m[t][bn][64] = x_row(16, w=9+t) @ W1 -------------
__global__ __launch_bounds__(256) void gemm1_kernel(const float* __restrict__ x,
                                                    const float* __restrict__ W1,
                                                    float* __restrict__ m) {
    int idx = blockIdx.x * blockDim.x + threadIdx.x;
    int oc = idx & 63;
    int bn = __builtin_amdgcn_readfirstlane(idx >> 6);   // wave-uniform -> s_loads on x
    int b = bn / N_NODES, n = bn - b * N_NODES;
    const float* xb = x + ((size_t)b * NW) * N_NODES * IN_F + (size_t)n * IN_F;
    const size_t S = (size_t)BN_TOT * HID;
    float s0 = 0.f, s1 = 0.f, s2 = 0.f;
#pragma unroll
    for (int f = 0; f < IN_F; ++f) {
        float wv = W1[f * HID + oc];
        s0 += xb[(size_t)9  * N_NODES * IN_F + f] * wv;
        s1 += xb[(size_t)10 * N_NODES * IN_F + f] * wv;
        s2 += xb[(size_t)11 * N_NODES * IN_F + f] * wv;
    }
    m[idx] = s0;
    m[S + idx] = s1;
    m[2 * S + idx] = s2;
}

// ---- gatherA x3: h1 = relu(agg(m1)+dinv^2*m1+b1); m2 = h1 @ W2 --------------
__global__ __launch_bounds__(256) void gatherA_kernel(
        const float* __restrict__ m, const int* __restrict__ row_ptr,
        const int* __restrict__ col, const float* __restrict__ ne,
        const float* __restrict__ dinv, const float* __restrict__ b1,
        const float* __restrict__ W2, float* __restrict__ m2) {
    __shared__ float hs[4][3][HID];
    int gid = blockIdx.x * blockDim.x + threadIdx.x;
    int lane = threadIdx.x & 63;
    int wv = threadIdx.x >> 6;
    int row = __builtin_amdgcn_readfirstlane(gid >> 6);  // -> s_loads on CSR
    const size_t S = (size_t)BN_TOT * HID;
    size_t ro = (size_t)row * HID + lane;
    float m0 = m[ro], m1v = m[S + ro], m2v = m[2 * S + ro];
    float s0, s1, s2;
    if (row < N_NODES) {
        float dv = dinv[row];
        float sn = dv * dv;
        s0 = sn * m0; s1 = sn * m1v; s2 = sn * m2v;
        int j = row_ptr[row], end = row_ptr[row + 1];
        for (; j + 1 < end; j += 2) {
            int c0 = col[j], c1 = col[j + 1];
            float w0 = ne[j], w1 = ne[j + 1];
            size_t o0 = (size_t)c0 * HID + lane, o1 = (size_t)c1 * HID + lane;
            s0 += w0 * m[o0] + w1 * m[o1];
            s1 += w0 * m[S + o0] + w1 * m[S + o1];
            s2 += w0 * m[2 * S + o0] + w1 * m[2 * S + o1];
        }
        if (j < end) {
            float w = ne[j];
            size_t o = (size_t)col[j] * HID + lane;
            s0 += w * m[o]; s1 += w * m[S + o]; s2 += w * m[2 * S + o];
        }
    } else {
        s0 = m0; s1 = m1v; s2 = m2v;   // deg=1, no in-edges
    }
    float bb = b1[lane];
    hs[wv][0][lane] = fmaxf(s0 + bb, 0.f);
    hs[wv][1][lane] = fmaxf(s1 + bb, 0.f);
    hs[wv][2][lane] = fmaxf(s2 + bb, 0.f);
    __syncthreads();
    float t0 = 0.f, t1 = 0.f, t2 = 0.f;
#pragma unroll
    for (int ic = 0; ic < HID; ++ic) {
        float w2v = W2[ic * HID + lane];
        t0 += hs[wv][0][ic] * w2v;
        t1 += hs[wv][1][ic] * w2v;
        t2 += hs[wv][2][ic] * w2v;
    }
    m2[ro] = t0;
    m2[S + ro] = t1;
    m2[2 * S + ro] = t2;
}

// ---- gatherBconv: H[t]=relu(agg+self+b2) for t=9,10,11 (in-wave), then ------
// conv1@t=10,11 + conv2@t=11 + relu + fc, one output per node. One wave/row.
// Lane roles for conv1: pos = lane>>5 (0 -> t10, 1 -> t11), tc = lane&31.
//   conv1[t] taps H[t-1+k], k=0..2 (k=2 is pad at t=11).
__global__ __launch_bounds__(256) void gatherBconv_kernel(
        const float* __restrict__ m, const int* __restrict__ row_ptr,
        const int* __restrict__ col, const float* __restrict__ ne,
        const float* __restrict__ dinv, const float* __restrict__ b2,
        const float* __restrict__ w1t, const float* __restrict__ b1c,
        const float* __restrict__ w2t, const float* __restrict__ b2c,
        const float* __restrict__ fcw, const float* __restrict__ fcb,
        float* __restrict__ out) {
    __shared__ float hs[4][3][HID];      // per-wave H rows (t = 9,10,11)
    __shared__ float c1s[4][2][TCH];     // per-wave conv1 outputs (t = 10,11)
    int gid = blockIdx.x * blockDim.x + threadIdx.x;
    int lane = threadIdx.x & 63;
    int wv = threadIdx.x >> 6;
    int row = __builtin_amdgcn_readfirstlane(gid >> 6);
    const size_t S = (size_t)BN_TOT * HID;
    size_t ro = (size_t)row * HID + lane;
    float m0 = m[ro], m1v = m[S + ro], m2v = m[2 * S + ro];
    float s0, s1, s2;
    if (row < N_NODES) {
        float dv = dinv[row];
        float sn = dv * dv;
        s0 = sn * m0; s1 = sn * m1v; s2 = sn * m2v;
        int j = row_ptr[row], end = row_ptr[row + 1];
        for (; j + 1 < end; j += 2) {
            int c0 = col[j], c1 = col[j + 1];
            float w0 = ne[j], w1 = ne[j + 1];
            size_t o0 = (size_t)c0 * HID + lane, o1 = (size_t)c1 * HID + lane;
            s0 += w0 * m[o0] + w1 * m[o1];
            s1 += w0 * m[S + o0] + w1 * m[S + o1];
            s2 += w0 * m[2 * S + o0] + w1 * m[2 * S + o1];
        }
        if (j < end) {
            float w = ne[j];
            size_t o = (size_t)col[j] * HID + lane;
            s0 += w * m[o]; s1 += w * m[S + o]; s2 += w * m[2 * S + o];
        }
    } else {
        s0 = m0; s1 = m1v; s2 = m2v;
    }
    float bb = b2[lane];
    hs[wv][0][lane] = fmaxf(s0 + bb, 0.f);   // H @ t=9
    hs[wv][1][lane] = fmaxf(s1 + bb, 0.f);   // H @ t=10
    hs[wv][2][lane] = fmaxf(s2 + bb, 0.f);   // H @ t=11
    __syncthreads();

    // ---- conv1: lane (pos,tc) computes c1[10+pos][tc] ----
    int pos = lane >> 5, tc = lane & 31;
    float acc = b1c[tc];
#pragma unroll 8
    for (int ic = 0; ic < HID; ++ic) {
        float w0 = w1t[(ic * 3 + 0) * 32 + tc];
        float w1 = w1t[(ic * 3 + 1) * 32 + tc];
        float w2 = w1t[(ic * 3 + 2) * 32 + tc];
        float hA = hs[wv][pos][ic];                      // t-1+0 = 9+pos
        float hB = hs[wv][pos + 1][ic];                  // t-1+1 = 10+pos
        float hC = (pos == 0) ? hs[wv][2][ic] : 0.f;     // t-1+2 = 11 (pad at pos=1)
        acc += hA * w0 + hB * w1 + hC * w2;
    }
    c1s[wv][pos][tc] = fmaxf(acc, 0.f);
    __syncthreads();

    // ---- conv2 @ t=11 (+relu, *fcw) on lanes 0..31; wave reduce; fc ----
    float r = 0.f;
    if (pos == 0) {
        float a2 = b2c[tc];
#pragma unroll 8
        for (int ic = 0; ic < TCH; ++ic) {
            a2 += c1s[wv][0][ic] * w2t[(ic * 2 + 0) * 32 + tc]
                + c1s[wv][1][ic] * w2t[(ic * 2 + 1) * 32 + tc];
        }
        r = fmaxf(a2, 0.f) * fcw[tc];
    }
#pragma unroll
    for (int off = 32; off > 0; off >>= 1) r += __shfl_down(r, off);
    if (lane == 0) out[row] = r + fcb[0];
}

extern "C" void kernel_launch(void* const* d_in, const int* in_sizes, int n_in,
                              void* d_out, int out_size, void* d_ws, size_t ws_size,
                              hipStream_t stream) {
    const float* x   = (const float*)d_in[0];
    const int*   ei  = (const int*)d_in[1];
    const float* W1  = (const float*)d_in[2];
    const float* b1  = (const float*)d_in[3];
    const float* W2  = (const float*)d_in[4];
    const float* b2  = (const float*)d_in[5];
    const float* c1w = (const float*)d_in[6];
    const float* c1b = (const float*)d_in[7];
    const float* c2w = (const float*)d_in[8];
    const float* c2b = (const float*)d_in[9];
    const float* fcw = (const float*)d_in[10];
    const float* fcb = (const float*)d_in[11];
    float* out = (float*)d_out;

    const int E = in_sizes[1] / 2;
    const int* src = ei;
    const int* dst = ei + E;

    // ---- workspace layout ----
    const size_t S = (size_t)BN_TOT * HID;
    int*   cnt      = (int*)d_ws;                  // 10000 (pad 10240)
    int*   row_ptr  = cnt + 10240;                 // 10001 (pad 10240)
    int*   fill_pos = row_ptr + 10240;             // 10000 (pad 10240)
    int*   colb     = fill_pos + 10240;            // E
    float* neb      = (float*)(colb + E);          // E
    float* dinv     = neb + E;                     // 10000 (pad 10240)
    float* w1t      = dinv + 10240;                // 6144
    float* w2t      = w1t + 6144;                  // 2048
    float* mA       = w2t + 2048;                  // 3*S
    float* mB       = mA + 3 * S;                  // 3*S

    // ---- CSR build + weight transpose ----
    hipMemsetAsync(cnt, 0, N_NODES * sizeof(int), stream);
    hist_kernel<<<(E + 255) / 256, 256, 0, stream>>>(dst, cnt, E);
    scan_kernel<<<1, 1024, 0, stream>>>(cnt, row_ptr, fill_pos, dinv);
    fill_kernel<<<(E + 255) / 256, 256, 0, stream>>>(src, dst, dinv, fill_pos, colb, neb, E);
    prep_kernel<<<32, 256, 0, stream>>>(c1w, c2w, w1t, w2t);

    const int NT = BN_TOT * HID;                   // 2,560,000 threads = 10000 blocks
    gemm1_kernel <<<NT / 256, 256, 0, stream>>>(x, W1, mA);
    gatherA_kernel<<<NT / 256, 256, 0, stream>>>(mA, row_ptr, colb, neb, dinv, b1, W2, mB);
    gatherBconv_kernel<<<NT / 256, 256, 0, stream>>>(mB, row_ptr, colb, neb, dinv, b2,
                                                     w1t, c1b, w2t, c2b, fcw, fcb, out);
}

// Round 8
// 207.439 us; speedup vs baseline: 10.1862x; 1.0345x over previous
//
#include <hip/hip_runtime.h>

#define N_NODES 10000
#define BN_TOT  40000
#define HID     64
#define IN_F    16
#define TCH     32
#define NW      12
#define RSTRIDE 192   // floats per row in interleaved m: [row][t=3][ch=64]

// ---------------- histogram of dst (degree = cnt + 1) ------------------------
__global__ void hist_kernel(const int* __restrict__ dst, int* __restrict__ cnt, int E) {
    int e = blockIdx.x * blockDim.x + threadIdx.x;
    if (e < E) atomicAdd(&cnt[dst[e]], 1);
}

// ---------------- single-block exclusive scan over 10000 bins ----------------
__global__ __launch_bounds__(1024) void scan_kernel(const int* __restrict__ cnt,
                                                    int* __restrict__ row_ptr,
                                                    int* __restrict__ fill_pos,
                                                    float* __restrict__ dinv) {
    __shared__ int part[1024];
    int t = threadIdx.x;
    int base = t * 10;
    int s = 0;
#pragma unroll
    for (int k = 0; k < 10; ++k) {
        int b = base + k;
        if (b < N_NODES) s += cnt[b];
    }
    part[t] = s;
    __syncthreads();
    for (int off = 1; off < 1024; off <<= 1) {
        int v = 0;
        if (t >= off) v = part[t - off];
        __syncthreads();
        part[t] += v;
        __syncthreads();
    }
    int running = (t == 0) ? 0 : part[t - 1];
#pragma unroll
    for (int k = 0; k < 10; ++k) {
        int b = base + k;
        if (b < N_NODES) {
            row_ptr[b]  = running;
            fill_pos[b] = running;
            int c = cnt[b];
            dinv[b] = rsqrtf((float)c + 1.0f);
            running += c;
        }
    }
    if (t == 1023) row_ptr[N_NODES] = part[1023];
}

// ---------------- CSR bucket fill: edge record = {src byte offset, ne} -------
__global__ void fill_kernel(const int* __restrict__ src, const int* __restrict__ dst,
                            const float* __restrict__ dinv,
                            int* __restrict__ fill_pos,
                            int2* __restrict__ edges, int E) {
    int e = blockIdx.x * blockDim.x + threadIdx.x;
    if (e >= E) return;
    int s = src[e], d = dst[e];
    int pos = atomicAdd(&fill_pos[d], 1);
    edges[pos] = make_int2(s * (RSTRIDE * 4), __float_as_int(dinv[s] * dinv[d]));
}

// ---------------- transpose conv weights for coalesced lane reads ------------
__global__ void prep_kernel(const float* __restrict__ c1w, const float* __restrict__ c2w,
                            float* __restrict__ w1t, float* __restrict__ w2t) {
    int idx = blockIdx.x * blockDim.x + threadIdx.x;   // 8192 threads
    if (idx < 6144) {
        int tc = idx & 31, r = idx >> 5;               // r = ic*3+k
        w1t[idx] = c1w[tc * 192 + r];
    } else {
        int i2 = idx - 6144;
        int tc = i2 & 31, r = i2 >> 5;                 // r = ic*2+k
        int ic = r >> 1, k = r & 1;
        w2t[i2] = c2w[tc * 96 + ic * 3 + k];
    }
}

// ---------------- GEMM1 x3: m[bn][t][64] = x_row(16, w=9+t) @ W1 -------------
__global__ __launch_bounds__(256) void gemm1_kernel(const float* __restrict__ x,
                                                    const float* __restrict__ W1,
                                                    float* __restrict__ m) {
    int idx = blockIdx.x * blockDim.x + threadIdx.x;
    int oc = idx & 63;
    int bn = __builtin_amdgcn_readfirstlane(idx >> 6);   // wave-uniform -> s_loads on x
    int b = bn / N_NODES, n = bn - b * N_NODES;
    const float* xb = x + ((size_t)b * NW) * N_NODES * IN_F + (size_t)n * IN_F;
    float s0 = 0.f, s1 = 0.f, s2 = 0.f;
#pragma unroll
    for (int f = 0; f < IN_F; ++f) {
        float wv = W1[f * HID + oc];
        s0 += xb[(size_t)9  * N_NODES * IN_F + f] * wv;
        s1 += xb[(size_t)10 * N_NODES * IN_F + f] * wv;
        s2 += xb[(size_t)11 * N_NODES * IN_F + f] * wv;
    }
    float* mr = m + (size_t)bn * RSTRIDE;
    mr[oc] = s0; mr[64 + oc] = s1; mr[128 + oc] = s2;
}

// ---- gatherA x3: h1 = relu(agg(m1)+dinv^2*m1+b1); m2 = h1 @ W2 --------------
// One wave per row, lane = channel. hs is per-wave -> wave_barrier only
// (DS ops from one wave complete in order; intrinsic fences compiler reorder).
__global__ __launch_bounds__(256) void gatherA_kernel(
        const float* __restrict__ m, const int* __restrict__ row_ptr,
        const int2* __restrict__ edges,
        const float* __restrict__ dinv, const float* __restrict__ b1,
        const float* __restrict__ W2, float* __restrict__ m2) {
    __shared__ float hs[4][3][HID];
    int gid = blockIdx.x * blockDim.x + threadIdx.x;
    int lane = threadIdx.x & 63;
    int wv = threadIdx.x >> 6;
    int row = __builtin_amdgcn_readfirstlane(gid >> 6);  // -> s_loads on CSR
    const float* mr = m + (size_t)row * RSTRIDE;
    float m0 = mr[lane], m1v = mr[64 + lane], m2v = mr[128 + lane];
    float s0, s1, s2;
    if (row < N_NODES) {
        float dv = dinv[row];
        float sn = dv * dv;
        s0 = sn * m0; s1 = sn * m1v; s2 = sn * m2v;
        int j = row_ptr[row], end = row_ptr[row + 1];
        for (; j + 3 < end; j += 4) {
            int2 e0 = edges[j], e1 = edges[j + 1], e2 = edges[j + 2], e3 = edges[j + 3];
            const float* p0 = (const float*)((const char*)m + e0.x);
            const float* p1 = (const float*)((const char*)m + e1.x);
            const float* p2 = (const float*)((const char*)m + e2.x);
            const float* p3 = (const float*)((const char*)m + e3.x);
            float w0 = __int_as_float(e0.y), w1 = __int_as_float(e1.y);
            float w2 = __int_as_float(e2.y), w3 = __int_as_float(e3.y);
            s0 += w0 * p0[lane]       + w1 * p1[lane]       + w2 * p2[lane]       + w3 * p3[lane];
            s1 += w0 * p0[64 + lane]  + w1 * p1[64 + lane]  + w2 * p2[64 + lane]  + w3 * p3[64 + lane];
            s2 += w0 * p0[128 + lane] + w1 * p1[128 + lane] + w2 * p2[128 + lane] + w3 * p3[128 + lane];
        }
        for (; j < end; ++j) {
            int2 e = edges[j];
            const float* p = (const float*)((const char*)m + e.x);
            float w = __int_as_float(e.y);
            s0 += w * p[lane]; s1 += w * p[64 + lane]; s2 += w * p[128 + lane];
        }
    } else {
        s0 = m0; s1 = m1v; s2 = m2v;   // deg=1, no in-edges
    }
    float bb = b1[lane];
    hs[wv][0][lane] = fmaxf(s0 + bb, 0.f);
    hs[wv][1][lane] = fmaxf(s1 + bb, 0.f);
    hs[wv][2][lane] = fmaxf(s2 + bb, 0.f);
    __builtin_amdgcn_wave_barrier();
    float t0 = 0.f, t1 = 0.f, t2 = 0.f;
#pragma unroll
    for (int ic = 0; ic < HID; ++ic) {
        float w2v = W2[ic * HID + lane];
        t0 += hs[wv][0][ic] * w2v;
        t1 += hs[wv][1][ic] * w2v;
        t2 += hs[wv][2][ic] * w2v;
    }
    float* m2r = m2 + (size_t)row * RSTRIDE;
    m2r[lane] = t0; m2r[64 + lane] = t1; m2r[128 + lane] = t2;
}

// ---- gatherBconv: H[t]=relu(agg+self+b2) t=9..11, conv1@10,11 + conv2@11 + fc
__global__ __launch_bounds__(256) void gatherBconv_kernel(
        const float* __restrict__ m, const int* __restrict__ row_ptr,
        const int2* __restrict__ edges,
        const float* __restrict__ dinv, const float* __restrict__ b2,
        const float* __restrict__ w1t, const float* __restrict__ b1c,
        const float* __restrict__ w2t, const float* __restrict__ b2c,
        const float* __restrict__ fcw, const float* __restrict__ fcb,
        float* __restrict__ out) {
    __shared__ float hs[4][3][HID];      // per-wave H rows (t = 9,10,11)
    __shared__ float c1s[4][2][TCH];     // per-wave conv1 outputs (t = 10,11)
    int gid = blockIdx.x * blockDim.x + threadIdx.x;
    int lane = threadIdx.x & 63;
    int wv = threadIdx.x >> 6;
    int row = __builtin_amdgcn_readfirstlane(gid >> 6);
    const float* mr = m + (size_t)row * RSTRIDE;
    float m0 = mr[lane], m1v = mr[64 + lane], m2v = mr[128 + lane];
    float s0, s1, s2;
    if (row < N_NODES) {
        float dv = dinv[row];
        float sn = dv * dv;
        s0 = sn * m0; s1 = sn * m1v; s2 = sn * m2v;
        int j = row_ptr[row], end = row_ptr[row + 1];
        for (; j + 3 < end; j += 4) {
            int2 e0 = edges[j], e1 = edges[j + 1], e2 = edges[j + 2], e3 = edges[j + 3];
            const float* p0 = (const float*)((const char*)m + e0.x);
            const float* p1 = (const float*)((const char*)m + e1.x);
            const float* p2 = (const float*)((const char*)m + e2.x);
            const float* p3 = (const float*)((const char*)m + e3.x);
            float w0 = __int_as_float(e0.y), w1 = __int_as_float(e1.y);
            float w2 = __int_as_float(e2.y), w3 = __int_as_float(e3.y);
            s0 += w0 * p0[lane]       + w1 * p1[lane]       + w2 * p2[lane]       + w3 * p3[lane];
            s1 += w0 * p0[64 + lane]  + w1 * p1[64 + lane]  + w2 * p2[64 + lane]  + w3 * p3[64 + lane];
            s2 += w0 * p0[128 + lane] + w1 * p1[128 + lane] + w2 * p2[128 + lane] + w3 * p3[128 + lane];
        }
        for (; j < end; ++j) {
            int2 e = edges[j];
            const float* p = (const float*)((const char*)m + e.x);
            float w = __int_as_float(e.y);
            s0 += w * p[lane]; s1 += w * p[64 + lane]; s2 += w * p[128 + lane];
        }
    } else {
        s0 = m0; s1 = m1v; s2 = m2v;
    }
    float bb = b2[lane];
    hs[wv][0][lane] = fmaxf(s0 + bb, 0.f);   // H @ t=9
    hs[wv][1][lane] = fmaxf(s1 + bb, 0.f);   // H @ t=10
    hs[wv][2][lane] = fmaxf(s2 + bb, 0.f);   // H @ t=11
    __builtin_amdgcn_wave_barrier();

    // ---- conv1: lane (pos,tc) computes c1[10+pos][tc] ----
    int pos = lane >> 5, tc = lane & 31;
    float acc = b1c[tc];
#pragma unroll 8
    for (int ic = 0; ic < HID; ++ic) {
        float w0 = w1t[(ic * 3 + 0) * 32 + tc];
        float w1 = w1t[(ic * 3 + 1) * 32 + tc];
        float w2 = w1t[(ic * 3 + 2) * 32 + tc];
        float hA = hs[wv][pos][ic];                      // t = 9+pos
        float hB = hs[wv][pos + 1][ic];                  // t = 10+pos
        float hC = (pos == 0) ? hs[wv][2][ic] : 0.f;     // t = 11 (pad at pos=1)
        acc += hA * w0 + hB * w1 + hC * w2;
    }
    c1s[wv][pos][tc] = fmaxf(acc, 0.f);
    __builtin_amdgcn_wave_barrier();

    // ---- conv2 @ t=11 (+relu, *fcw) on lanes 0..31; wave reduce; fc ----
    float r = 0.f;
    if (pos == 0) {
        float a2 = b2c[tc];
#pragma unroll 8
        for (int ic = 0; ic < TCH; ++ic) {
            a2 += c1s[wv][0][ic] * w2t[(ic * 2 + 0) * 32 + tc]
                + c1s[wv][1][ic] * w2t[(ic * 2 + 1) * 32 + tc];
        }
        r = fmaxf(a2, 0.f) * fcw[tc];
    }
#pragma unroll
    for (int off = 32; off > 0; off >>= 1) r += __shfl_down(r, off);
    if (lane == 0) out[row] = r + fcb[0];
}

extern "C" void kernel_launch(void* const* d_in, const int* in_sizes, int n_in,
                              void* d_out, int out_size, void* d_ws, size_t ws_size,
                              hipStream_t stream) {
    const float* x   = (const float*)d_in[0];
    const int*   ei  = (const int*)d_in[1];
    const float* W1  = (const float*)d_in[2];
    const float* b1  = (const float*)d_in[3];
    const float* W2  = (const float*)d_in[4];
    const float* b2  = (const float*)d_in[5];
    const float* c1w = (const float*)d_in[6];
    const float* c1b = (const float*)d_in[7];
    const float* c2w = (const float*)d_in[8];
    const float* c2b = (const float*)d_in[9];
    const float* fcw = (const float*)d_in[10];
    const float* fcb = (const float*)d_in[11];
    float* out = (float*)d_out;

    const int E = in_sizes[1] / 2;
    const int* src = ei;
    const int* dst = ei + E;

    // ---- workspace layout ----
    const size_t S3 = (size_t)BN_TOT * RSTRIDE;    // 7,680,000 floats per m-buffer
    int*   cnt      = (int*)d_ws;                  // 10240
    int*   row_ptr  = cnt + 10240;                 // 10240
    int*   fill_pos = row_ptr + 10240;             // 10240
    int2*  edges    = (int2*)(fill_pos + 10240);   // E records (8 B each)
    float* dinv     = (float*)(edges + E);         // 10240
    float* w1t      = dinv + 10240;                // 6144
    float* w2t      = w1t + 6144;                  // 2048
    float* mA       = w2t + 2048;                  // S3
    float* mB       = mA + S3;                     // S3

    // ---- CSR build + weight transpose ----
    hipMemsetAsync(cnt, 0, N_NODES * sizeof(int), stream);
    hist_kernel<<<(E + 255) / 256, 256, 0, stream>>>(dst, cnt, E);
    scan_kernel<<<1, 1024, 0, stream>>>(cnt, row_ptr, fill_pos, dinv);
    fill_kernel<<<(E + 255) / 256, 256, 0, stream>>>(src, dst, dinv, fill_pos, edges, E);
    prep_kernel<<<32, 256, 0, stream>>>(c1w, c2w, w1t, w2t);

    const int NT = BN_TOT * HID;                   // 2,560,000 threads = 10000 blocks
    gemm1_kernel <<<NT / 256, 256, 0, stream>>>(x, W1, mA);
    gatherA_kernel<<<NT / 256, 256, 0, stream>>>(mA, row_ptr, edges, dinv, b1, W2, mB);
    gatherBconv_kernel<<<NT / 256, 256, 0, stream>>>(mB, row_ptr, edges, dinv, b2,
                                                     w1t, c1b, w2t, c2b, fcw, fcb, out);
}